// Round 14
// baseline (429.746 us; speedup 1.0000x reference)
//
#include <hip/hip_runtime.h>
#include <math.h>

#define Bq 64
#define Hq 256
#define Lq 1024
#define HLq (Hq*Lq)        // 262144
#define BHLq (Bq*Hq*Lq)    // 16777216
#define HNq (Hq*64)        // 16384

typedef __attribute__((ext_vector_type(8))) short bf16x8;
typedef __attribute__((ext_vector_type(4))) float f32x4;

__device__ __forceinline__ float sigmoidf_(float x){ return 1.f/(1.f+expf(-x)); }
__device__ __forceinline__ unsigned short f2bf(float f){
  unsigned u = __float_as_uint(f);
  u += 0x7FFF + ((u>>16)&1);
  return (unsigned short)(u>>16);
}
__device__ __forceinline__ float bf2f(unsigned short h){ return __uint_as_float(((unsigned)h)<<16); }

// ---------------- K1a: ada linear partials. Grid (32 o-tiles, 16 k-chunks), 512 blocks.
__global__ __launch_bounds__(256) void k_ada2(const int* __restrict__ tptr,
        const float* __restrict__ ada_w, float* __restrict__ Part){
  __shared__ float Es[64][68];
  __shared__ float Ws[64][68];
  const int tid = threadIdx.x;
  const int o0 = blockIdx.x * 64;
  const int kc = blockIdx.y;
  const int k0 = kc * 64;
  const float ci = -logf(10000.f) / 511.f;
  #pragma unroll
  for (int it = 0; it < 4; ++it){
    int fidx = it*256 + tid;
    int row = fidx >> 4;        // b
    int c4  = fidx & 15;
    float tb = (float)tptr[row];
    float4 v;
    float* vp = &v.x;
    #pragma unroll
    for (int q = 0; q < 4; ++q){
      int k = k0 + c4*4 + q;
      float f = expf(ci * (float)(k & 511));
      float arg = tb * f;
      float s = (k < 512) ? sinf(arg) : cosf(arg);
      vp[q] = s * sigmoidf_(s);
    }
    *(float4*)&Es[row][c4*4] = v;
  }
  #pragma unroll
  for (int it = 0; it < 4; ++it){
    int fidx = it*256 + tid;
    int row = fidx >> 4;        // o
    int c4  = fidx & 15;
    *(float4*)&Ws[row][c4*4] = *(const float4*)(ada_w + (size_t)(o0+row)*1024 + k0 + c4*4);
  }
  __syncthreads();
  float acc[4][4] = {};
  #pragma unroll
  for (int ks = 0; ks < 16; ++ks){
    int k = ks*4;
    float4 ev[4], wv[4];
    #pragma unroll
    for (int i=0;i<4;++i) ev[i] = *(const float4*)&Es[(tid>>4) + 16*i][k];
    #pragma unroll
    for (int j=0;j<4;++j) wv[j] = *(const float4*)&Ws[(tid&15) + 16*j][k];
    #pragma unroll
    for (int i=0;i<4;++i)
      #pragma unroll
      for (int j=0;j<4;++j)
        acc[i][j] += ev[i].x*wv[j].x + ev[i].y*wv[j].y + ev[i].z*wv[j].z + ev[i].w*wv[j].w;
  }
  float* pbase = Part + (size_t)kc*131072 + o0;   // Part[kc][b][o]
  #pragma unroll
  for (int i=0;i<4;++i){
    int b = (tid>>4) + 16*i;
    #pragma unroll
    for (int j=0;j<4;++j){
      int o = (tid&15) + 16*j;
      pbase[(size_t)b*2048 + o] = acc[i][j];
    }
  }
}

// ---------------- K1b: reduce 16 K-partials + bias -> scsh (B x 2048)
__global__ void k_red(const float* __restrict__ Part, const float* __restrict__ ada_b,
                      float* __restrict__ scsh){
  int idx = blockIdx.x*256 + threadIdx.x;   // float4 index, 32768 total
  float4 s = ((const float4*)ada_b)[idx & 511];
  #pragma unroll
  for (int p = 0; p < 16; ++p){
    float4 u = ((const float4*)Part)[p*32768 + idx];
    s.x += u.x; s.y += u.y; s.z += u.z; s.w += u.w;
  }
  ((float4*)scsh)[idx] = s;
}

// ---------------- K1c: convert out_w / lin1_w / lin2_w (256x256 fp32) -> bf16, L2-resident
__global__ void k_wcvt(const float* __restrict__ w0, const float* __restrict__ w1,
                       const float* __restrict__ w2, unsigned short* __restrict__ wb){
  int idx = blockIdx.x*256 + threadIdx.x;   // float4 units, 49152 total
  const float* src = (idx < 16384) ? w0 : ((idx < 32768) ? w1 : w2);
  int loc = idx & 16383;
  float4 v = ((const float4*)src)[loc];
  uint2 pk;
  pk.x = (unsigned)f2bf(v.x) | ((unsigned)f2bf(v.y)<<16);
  pk.y = (unsigned)f2bf(v.z) | ((unsigned)f2bf(v.w)<<16);
  ((uint2*)wb)[idx] = pk;
}

// ---------------- K2: AdaLayerNorm over L per (b,h) row -> Ax (fp32)
__global__ void k_adaln(const float* __restrict__ x, const float* __restrict__ scsh,
                        float* __restrict__ A){
  const int bid = blockIdx.x;        // b*H + h
  const int b = bid >> 8;
  const int tid = threadIdx.x;
  const float4* row = (const float4*)(x + (size_t)bid*1024);
  float4 v = row[tid];
  float s = v.x+v.y+v.z+v.w;
  float ss = v.x*v.x+v.y*v.y+v.z*v.z+v.w*v.w;
  #pragma unroll
  for (int off=32; off; off>>=1){ s += __shfl_xor(s,off); ss += __shfl_xor(ss,off); }
  __shared__ float rs_[4], rss_[4];
  int lane = tid & 63, w = tid >> 6;
  if (!lane){ rs_[w]=s; rss_[w]=ss; }
  __syncthreads();
  s  = rs_[0]+rs_[1]+rs_[2]+rs_[3];
  ss = rss_[0]+rss_[1]+rss_[2]+rss_[3];
  float mean = s * (1.f/1024.f);
  float var  = ss*(1.f/1024.f) - mean*mean;
  float rstd = rsqrtf(var + 1e-5f);
  float4 sc = ((const float4*)(scsh + b*2048))[tid];
  float4 sh = ((const float4*)(scsh + b*2048 + 1024))[tid];
  float4 o;
  o.x = (v.x-mean)*rstd*(1.f+sc.x) + sh.x;
  o.y = (v.y-mean)*rstd*(1.f+sc.y) + sh.y;
  o.z = (v.z-mean)*rstd*(1.f+sc.z) + sh.z;
  o.w = (v.w-mean)*rstd*(1.f+sc.w) + sh.w;
  ((float4*)(A + (size_t)bid*1024))[tid] = o;
}

// ---------------- K3: channel-LN v3 — fused stats+normalize, WIDE access.
// Block = (128-l chunk, b): 256 thr = 32 l-float4 x 8 h-chunks; grid (8,64)=512.
// Loads float4 (16B/lane, was 4B); stores ushort4 (8B/lane, 256B/wave-row, was 2B).
__global__ __launch_bounds__(256) void k_chln3(const float* __restrict__ A,
        const float* __restrict__ nw, const float* __restrict__ nb,
        unsigned short* __restrict__ Zb){
  const int b  = blockIdx.y;
  const int lq = threadIdx.x & 31;          // float4 group within 128-l chunk
  const int hc = threadIdx.x >> 5;          // 0..7
  const int l4 = blockIdx.x*32 + lq;        // float4 index in row (0..255)
  const float4* pA = (const float4*)(A + (size_t)b*HLq) + (size_t)hc*32*256 + l4;
  float4 s = {0.f,0.f,0.f,0.f}, ss = {0.f,0.f,0.f,0.f};
  #pragma unroll 4
  for (int i = 0; i < 32; ++i){
    float4 v = pA[(size_t)i*256];
    s.x += v.x; s.y += v.y; s.z += v.z; s.w += v.w;
    ss.x += v.x*v.x; ss.y += v.y*v.y; ss.z += v.z*v.z; ss.w += v.w*v.w;
  }
  __shared__ float4 sp[8][32], ssp[8][32];
  __shared__ float4 mS[32], rS[32];
  sp[hc][lq] = s; ssp[hc][lq] = ss;
  __syncthreads();
  if (threadIdx.x < 32){
    int q = threadIdx.x;
    float4 st = {0.f,0.f,0.f,0.f}, sst = {0.f,0.f,0.f,0.f};
    #pragma unroll
    for (int c = 0; c < 8; ++c){
      float4 a = sp[c][q], bb2 = ssp[c][q];
      st.x += a.x; st.y += a.y; st.z += a.z; st.w += a.w;
      sst.x += bb2.x; sst.y += bb2.y; sst.z += bb2.z; sst.w += bb2.w;
    }
    float4 m, r;
    m.x = st.x*(1.f/256.f); r.x = rsqrtf(sst.x*(1.f/256.f) - m.x*m.x + 1e-5f);
    m.y = st.y*(1.f/256.f); r.y = rsqrtf(sst.y*(1.f/256.f) - m.y*m.y + 1e-5f);
    m.z = st.z*(1.f/256.f); r.z = rsqrtf(sst.z*(1.f/256.f) - m.z*m.z + 1e-5f);
    m.w = st.w*(1.f/256.f); r.w = rsqrtf(sst.w*(1.f/256.f) - m.w*m.w + 1e-5f);
    mS[q] = m; rS[q] = r;
  }
  __syncthreads();
  float4 m4 = mS[lq], r4 = rS[lq];
  unsigned short* zb = Zb + (size_t)b*HLq;
  #pragma unroll 4
  for (int i = 0; i < 32; ++i){
    int h = hc*32 + i;
    float4 v = pA[(size_t)i*256];
    float w_ = nw[h], bb = nb[h];
    unsigned short o0 = f2bf((v.x-m4.x)*r4.x*w_ + bb);
    unsigned short o1 = f2bf((v.y-m4.y)*r4.y*w_ + bb);
    unsigned short o2 = f2bf((v.z-m4.z)*r4.z*w_ + bb);
    unsigned short o3 = f2bf((v.w-m4.w)*r4.w*w_ + bb);
    uint2 pk;
    pk.x = (unsigned)o0 | ((unsigned)o1<<16);
    pk.y = (unsigned)o2 | ((unsigned)o3<<16);
    *(uint2*)(zb + (size_t)h*1024 + l4*4) = pk;
  }
}

// ---------------- K4: SSM kernels K0/K1 (2,H,L) via direct Vandermonde sum (fp32)
__global__ void k_ssmk(const float* __restrict__ log_dt, const float* __restrict__ A_re,
                       const float* __restrict__ A_im, const float* __restrict__ C_re,
                       const float* __restrict__ C_im, float* __restrict__ Kbuf){
  const int h = blockIdx.y;
  const int tid = threadIdx.x;
  __shared__ float dre[64], dim_[64], c0r[64], c0i[64], c1r[64], c1i[64];
  if (tid < 64){
    int n = tid;
    float dt = expf(log_dt[h]);
    float Ar = -expf(A_re[h*64+n]);
    float Ai = A_im[h*64+n];
    float dr = dt*Ar, di = dt*Ai;
    float er = expf(dr);
    float dAr = er*cosf(di), dAi = er*sinf(di);
    float den = Ar*Ar + Ai*Ai;
    float nr = dAr - 1.f, ni = dAi;
    float qr = (nr*Ar + ni*Ai)/den;
    float qi = (ni*Ar - nr*Ai)/den;
    float C0r = C_re[h*64+n],       C0i = C_im[h*64+n];
    float C1r = C_re[HNq + h*64+n], C1i = C_im[HNq + h*64+n];
    c0r[n] = C0r*qr - C0i*qi; c0i[n] = C0r*qi + C0i*qr;
    c1r[n] = C1r*qr - C1i*qi; c1i[n] = C1r*qi + C1i*qr;
    dre[n] = dr; dim_[n] = di;
  }
  __syncthreads();
  int l = blockIdx.x*256 + tid;
  float lf = (float)l;
  float a0=0.f, a1=0.f;
  for (int n=0;n<64;++n){
    float e  = expf(lf*dre[n]);
    float ph = lf*dim_[n];
    float wr = e*cosf(ph), wi = e*sinf(ph);
    a0 += c0r[n]*wr - c0i[n]*wi;
    a1 += c1r[n]*wr - c1i[n]*wi;
  }
  Kbuf[h*1024 + l]       = 2.f*a0;
  Kbuf[HLq + h*1024 + l] = 2.f*a1;
}

// ---------------- K5: bidirectional Toeplitz conv (v2: 512 thr / 8 waves).
__global__ __launch_bounds__(512,2) void k_conv(const unsigned short* __restrict__ Zb,
        const float* __restrict__ Kbuf, const float* __restrict__ Dp,
        unsigned short* __restrict__ Cb){
  __shared__ unsigned short kcopy[8][2056];   // stride 2056 el = 1028 dw = 4 mod 32 (bank spread)
  __shared__ unsigned short As[64][136];      // z tile, Kc=128, +8 pad
  const int tid = threadIdx.x;
  const int h  = blockIdx.y;
  const int l0 = blockIdx.x * 512;
  const float* K0 = Kbuf + h*1024;
  const float* K1 = Kbuf + HLq + h*1024;
  for (int idx = tid; idx < 8*2056; idx += 512){
    int s = idx / 2056;
    int i = idx - s*2056;
    int q = 2046 - i - s;
    float v = 0.f;
    if (q >= 0) v = (q >= 1023) ? K0[q-1023] : K1[1022-q];
    kcopy[s][i] = f2bf(v);
  }
  const int lane = tid & 63;
  const int w    = tid >> 6;      // 0..7
  const int ln   = lane & 15;
  const int quad = lane >> 4;
  int kofs[4];
  #pragma unroll
  for (int nt=0; nt<4; ++nt){
    int l = l0 + w*64 + nt*16 + ln;
    int d = 1023 - l;              // krev base = d + j
    int s = d & 7;
    kofs[nt] = s*2056 + (d - s) + quad*8;   // 16B-aligned element offset
  }
  const unsigned short* kbase = &kcopy[0][0];
  f32x4 acc[4][4] = {};
  for (int c = 0; c < 8; ++c){
    __syncthreads();
    #pragma unroll
    for (int pass = 0; pass < 2; ++pass){
      int b = pass*32 + (tid>>4);
      int col = (tid & 15)*8;
      *(uint4*)&As[b][col] = *(const uint4*)(Zb + ((size_t)b*256 + h)*1024 + c*128 + col);
    }
    __syncthreads();
    #pragma unroll
    for (int ks = 0; ks < 4; ++ks){
      int kk = ks*32 + quad*8;
      bf16x8 af[4];
      #pragma unroll
      for (int mt=0; mt<4; ++mt) af[mt] = *(const bf16x8*)&As[mt*16+ln][kk];
      int jb = c*128 + ks*32;
      bf16x8 bv[4];
      #pragma unroll
      for (int nt=0; nt<4; ++nt) bv[nt] = *(const bf16x8*)(kbase + kofs[nt] + jb);
      #pragma unroll
      for (int mt=0; mt<4; ++mt)
        #pragma unroll
        for (int nt=0; nt<4; ++nt)
          acc[mt][nt] = __builtin_amdgcn_mfma_f32_16x16x32_bf16(af[mt], bv[nt], acc[mt][nt], 0,0,0);
    }
  }
  float Dh = Dp[h];
  #pragma unroll
  for (int mt=0; mt<4; ++mt){
    #pragma unroll
    for (int reg=0; reg<4; ++reg){
      int b = mt*16 + quad*4 + reg;
      const unsigned short* zrow = Zb + ((size_t)b*256+h)*1024;
      unsigned short* crow = Cb + ((size_t)b*256+h)*1024;
      #pragma unroll
      for (int nt=0; nt<4; ++nt){
        int l = l0 + w*64 + nt*16 + ln;
        float y = acc[mt][nt][reg] + Dh*bf2f(zrow[l]);
        float g = 0.5f*y*(1.f + erff(y*0.70710678118f));
        crow[l] = f2bf(g);
      }
    }
  }
}

// ---------------- K6: FUSED gate + dual output GEMM (v8 — measured 89us).
__global__ __launch_bounds__(512,4)
void k_fuse(const unsigned short* __restrict__ U,
        const unsigned short* __restrict__ Wob, const float* __restrict__ out_b,
        const unsigned short* __restrict__ W1b, const float* __restrict__ b1,
        const unsigned short* __restrict__ W2b, const float* __restrict__ b2,
        const float* __restrict__ Ax, float* __restrict__ out){
  __shared__ unsigned short Ts[64][264];
  const int tid = threadIdx.x;
  const int l0 = blockIdx.x * 64;
  const int b  = blockIdx.y;
  const int lane = tid & 63, w = tid >> 6, ln = lane & 15, quad = lane >> 4;
  // ---- stage: Ts[l][i] = U[b][i][l0+l]  (transpose gather, 4 i per uint2)
  {
    int l   = tid & 63;
    int grp = tid >> 6;            // 0..7
    #pragma unroll
    for (int it = 0; it < 8; ++it){
      int i4 = it*8 + grp;         // 0..63
      const unsigned short* usrc = U + ((size_t)b*256 + i4*4)*1024 + l0 + l;
      unsigned short e0 = usrc[0], e1 = usrc[1024], e2 = usrc[2048], e3 = usrc[3072];
      uint2 val; val.x = (unsigned)e0 | ((unsigned)e1<<16); val.y = (unsigned)e2 | ((unsigned)e3<<16);
      *(uint2*)&Ts[l][i4*4] = val;
    }
  }
  __syncthreads();
  // ---- GEMM1 + gate, two o-halves (16 o-rows each); g packed in regs
  uint2 gpk[2][4];   // [half][nt]
  #pragma unroll
  for (int half = 0; half < 2; ++half){
    f32x4 acc1[4] = {};
    #pragma unroll
    for (int ks = 0; ks < 8; ++ks){
      int kk = ks*32 + quad*8;
      bf16x8 af = *(const bf16x8*)(Wob + (size_t)(w*32+half*16+ln)*256 + kk);
      bf16x8 bv[4];
      #pragma unroll
      for (int nt=0;nt<4;++nt) bv[nt] = *(const bf16x8*)&Ts[nt*16+ln][kk];
      #pragma unroll
      for (int nt=0;nt<4;++nt)
        acc1[nt] = __builtin_amdgcn_mfma_f32_16x16x32_bf16(af, bv[nt], acc1[nt],0,0,0);
    }
    // gate: g = tanh(v)*sigmoid(v) = (1-t)/(1+t^2), t = e^-v (clamped)
    #pragma unroll
    for (int reg=0;reg<4;++reg){
      int o = w*32 + half*16 + quad*4 + reg;
      float bo = out_b[o];
      const float* arow = Ax + ((size_t)b*256 + o)*1024 + l0;
      #pragma unroll
      for (int nt=0;nt<4;++nt){
        int l = nt*16 + ln;
        float v = acc1[nt][reg] + bo + arow[l];
        float t = expf(-fmaxf(v, -15.f));
        acc1[nt][reg] = (1.f - t)/(1.f + t*t);
      }
    }
    #pragma unroll
    for (int nt=0;nt<4;++nt){
      uint2 pk;
      pk.x = (unsigned)f2bf(acc1[nt][0]) | ((unsigned)f2bf(acc1[nt][1])<<16);
      pk.y = (unsigned)f2bf(acc1[nt][2]) | ((unsigned)f2bf(acc1[nt][3])<<16);
      gpk[half][nt] = pk;
    }
  }
  __syncthreads();            // all waves done reading u from Ts
  // ---- write g into the same tile; column dim is now o
  #pragma unroll
  for (int half=0;half<2;++half){
    int ob = w*32 + half*16 + quad*4;
    #pragma unroll
    for (int nt=0;nt<4;++nt){
      int l = nt*16 + ln;
      *(uint2*)&Ts[l][ob] = gpk[half][nt];
    }
  }
  __syncthreads();
  // ---- GEMM2 (dual), two o-halves: live accs 32 VGPR
  #pragma unroll
  for (int half = 0; half < 2; ++half){
    f32x4 accA[4] = {}, accB[4] = {};
    #pragma unroll
    for (int ks = 0; ks < 8; ++ks){
      int kk = ks*32 + quad*8;
      bf16x8 bv[4];
      #pragma unroll
      for (int nt=0;nt<4;++nt) bv[nt] = *(const bf16x8*)&Ts[nt*16+ln][kk];
      int orow = w*32 + half*16 + ln;
      bf16x8 a1 = *(const bf16x8*)(W1b + (size_t)orow*256 + kk);
      #pragma unroll
      for (int nt=0;nt<4;++nt)
        accA[nt] = __builtin_amdgcn_mfma_f32_16x16x32_bf16(a1, bv[nt], accA[nt],0,0,0);
      bf16x8 a2 = *(const bf16x8*)(W2b + (size_t)orow*256 + kk);
      #pragma unroll
      for (int nt=0;nt<4;++nt)
        accB[nt] = __builtin_amdgcn_mfma_f32_16x16x32_bf16(a2, bv[nt], accB[nt],0,0,0);
    }
    // epilogue for this half (Ax re-read; L2-hot)
    #pragma unroll
    for (int reg=0;reg<4;++reg){
      int o = w*32 + half*16 + quad*4 + reg;
      float bo1 = b1[o], bo2 = b2[o];
      const float* arow = Ax + ((size_t)b*256 + o)*1024 + l0;
      float* o1row = out + ((size_t)b*256 + o)*1024 + l0;
      float* o2row = o1row + BHLq;
      #pragma unroll
      for (int nt=0;nt<4;++nt){
        int l = nt*16 + ln;
        o1row[l] = accA[nt][reg] + bo1 + arow[l];
        o2row[l] = accB[nt][reg] + bo2;
      }
    }
  }
}

extern "C" void kernel_launch(void* const* d_in, const int* in_sizes, int n_in,
                              void* d_out, int out_size, void* d_ws, size_t ws_size,
                              hipStream_t stream){
  const float* x      = (const float*)d_in[0];
  const int*   t      = (const int*)  d_in[1];
  const float* ada_w  = (const float*)d_in[2];
  const float* ada_b  = (const float*)d_in[3];
  const float* norm_w = (const float*)d_in[4];
  const float* norm_b = (const float*)d_in[5];
  const float* log_dt = (const float*)d_in[6];
  const float* A_re   = (const float*)d_in[7];
  const float* A_im   = (const float*)d_in[8];
  const float* C_re   = (const float*)d_in[9];
  const float* C_im   = (const float*)d_in[10];
  const float* Dp     = (const float*)d_in[11];
  const float* out_w  = (const float*)d_in[12];
  const float* out_b  = (const float*)d_in[13];
  const float* lin1_w = (const float*)d_in[14];
  const float* lin1_b = (const float*)d_in[15];
  const float* lin2_w = (const float*)d_in[16];
  const float* lin2_b = (const float*)d_in[17];

  float* Ax            = (float*)d_ws;                     // x1 fp32, BHL
  unsigned short* Zb   = (unsigned short*)(Ax + BHLq);     // z bf16, BHL
  unsigned short* Cb   = Zb + BHLq;                        // gelu(y) bf16, BHL
  float* Kbuf          = (float*)(Cb + BHLq);              // 2*H*L fp32
  float* Part          = Kbuf + 2*HLq;                     // 16 x B x 2048 fp32 partials
  float* scsh          = Part + 16*64*2048;                // B*2048 fp32
  unsigned short* wb   = (unsigned short*)(scsh + 64*2048);// 3 x 256*256 bf16 weights
  float* out           = (float*)d_out;

  k_wcvt  <<<192, 256, 0, stream>>>(out_w, lin1_w, lin2_w, wb);
  k_ada2  <<<dim3(32, 16), 256, 0, stream>>>(t, ada_w, Part);
  k_red   <<<128, 256, 0, stream>>>(Part, ada_b, scsh);
  k_adaln <<<Bq*Hq, 256, 0, stream>>>(x, scsh, Ax);
  k_chln3 <<<dim3(8, Bq), 256, 0, stream>>>(Ax, norm_w, norm_b, Zb);
  k_ssmk  <<<dim3(4, Hq), 256, 0, stream>>>(log_dt, A_re, A_im, C_re, C_im, Kbuf);
  k_conv  <<<dim3(2, Hq), 512, 0, stream>>>(Zb, Kbuf, Dp, Cb);
  k_fuse  <<<dim3(16, Bq), 512, 0, stream>>>(Cb, wb, out_b, wb + 65536, lin1_b,
                                             wb + 131072, lin2_b, Ax, out);
}